// Round 11
// baseline (1250.298 us; speedup 1.0000x reference)
//
#include <hip/hip_runtime.h>
#include <stdint.h>

// ---------------------------------------------------------------------------
// GCN block: 3 x [ h = leaky_relu(in @ W);  out = adj@h + h ]   (I folded OUT)
// B=64, N=4096, D=16.  GEMM M=4096 x C=1024 x K=4096 in FP8 e4m3, fp32 accum,
// MX-scaled mfma_scale_16x16x128 with unit scales.
// Round 17: r16's hipLaunchCooperativeKernel likely poisoned the harness's
// stream capture (coop launch is not capturable; fallback can't rescue an
// invalidated capture).  Same single-launch plan, plain-launch vehicle:
// persistent kernel, 512 blocks x 512 thr, co-residency GUARANTEED by
// resources (64KB static LDS -> hard 2 blocks/CU; launch_bounds(512,4) ->
// VGPR<=128; 512 = 256CU x 2), software grid barrier = device-scope atomic
// arrive + spin on a __device__ counter (monotonic targets k*512, zeroed
// per-iteration by a capturable 64B hipMemsetAsync on the symbol).
// Phases (all verified code from r12/r15, byte-identical math):
//   [adj8 quant || linear0] -> gemm0 -> linear1 -> gemm1 -> linear2
//   -> gemm2 -> add_out, separated by 6 grid barriers + device fences.
// ws: adj8 16MB | hb8 4MB | h_nc 8MB | p0 8MB | p1 8MB = 44MB
// ---------------------------------------------------------------------------

typedef float  f32x4  __attribute__((ext_vector_type(4)));
typedef unsigned short ushort8 __attribute__((ext_vector_type(8)));
typedef int    i32x4  __attribute__((ext_vector_type(4)));
typedef int    i32x8  __attribute__((ext_vector_type(8)));

typedef __attribute__((address_space(1))) void* as1p;
typedef __attribute__((address_space(3))) void* as3p;
#define GLOAD_LDS16(G, L) \
  __builtin_amdgcn_global_load_lds((as1p)(G), (as3p)(L), 16, 0, 0)

#define P_ELEMS 4194304       // elems per partial buffer (4096*1024)
#define ADJ_SCALE 4096.0f
#define ADJ_DESCALE (1.0f / 4096.0f)
#define SCALE_ONE 0x7f7f7f7f  // e8m0 exponent 127 = 2^0 = 1.0 in every byte

__device__ __attribute__((aligned(64))) unsigned g_bar[16];

__device__ __forceinline__ unsigned short f2bf(float f) {
  unsigned u = __float_as_uint(f);
  u += 0x7fffu + ((u >> 16) & 1u);  // RNE
  return (unsigned short)(u >> 16);
}
__device__ __forceinline__ float bf2f(unsigned short u) {
  return __uint_as_float(((unsigned)u) << 16);
}
// pack 4 fp32 -> 4 fp8 e4m3 bytes (RNE, saturating)
__device__ __forceinline__ int pk4_fp8(float a, float b, float c, float d) {
  int v = __builtin_amdgcn_cvt_pk_fp8_f32(a, b, 0, false);   // bytes 0,1
  v = __builtin_amdgcn_cvt_pk_fp8_f32(c, d, v, true);        // bytes 2,3
  return v;
}

// grid barrier: all 512 blocks arrive (device-scope atomic), spin until the
// monotonic counter reaches `target`.  Co-residency guaranteed by resources
// (see header).  threadfence = device scope -> cross-XCD safe (G16).
__device__ __forceinline__ void grid_bar(unsigned target) {
  __syncthreads();
  if (threadIdx.x == 0) {
    __threadfence();                       // publish this block's writes
    atomicAdd(&g_bar[0], 1u);
    while (__hip_atomic_load(&g_bar[0], __ATOMIC_ACQUIRE,
                             __HIP_MEMORY_SCOPE_AGENT) < target)
      __builtin_amdgcn_s_sleep(2);
    __threadfence();                       // acquire all blocks' writes
  }
  __syncthreads();
}

// ---------------------------------------------------------------------------
// one 64n x 64c linear tile, executed by a 256-thread half (t = tid&255).
// sm points at this half's 26KB LDS slice.  Contains __syncthreads();
// both halves execute the same call sites (uniform).
// ---------------------------------------------------------------------------
__device__ __forceinline__ void lin0_tile(const float* __restrict__ x,
                                          const float* __restrict__ W,
                                          unsigned char* __restrict__ hb8,
                                          unsigned short* __restrict__ hnc_out,
                                          int n0, int c0, int t,
                                          unsigned char* sm) {
  float* xs = (float*)sm;                              // 64*65*4 = 16640 B
  unsigned short* ht = (unsigned short*)(sm + 16640);  // 64*72*2 = 9216 B

  for (int i = t; i < 1024; i += 256) {
    int bs = i >> 8, rem = i & 255, nr = rem >> 2, d4 = rem & 3;
    float4 v = *(const float4*)(
        x + ((size_t)(c0 / 16 + bs) * 4096 + n0 + nr) * 16 + d4 * 4);
    float* dst = xs + nr * 65 + bs * 16 + d4 * 4;
    dst[0] = v.x; dst[1] = v.y; dst[2] = v.z; dst[3] = v.w;
  }
  __syncthreads();

  int n_l = t & 63, b_l = t >> 6;                      // b_l 0..3
  float xv[16];
#pragma unroll
  for (int d = 0; d < 16; ++d) xv[d] = xs[n_l * 65 + b_l * 16 + d];
  float accv[16];
#pragma unroll
  for (int e = 0; e < 16; ++e) accv[e] = 0.f;
#pragma unroll
  for (int d = 0; d < 16; ++d)
#pragma unroll
    for (int e = 0; e < 16; ++e) accv[e] += xv[d] * W[d * 16 + e];

  ushort8 h0, h1;
#pragma unroll
  for (int e = 0; e < 16; ++e) {
    float a = accv[e] > 0.f ? accv[e] : 0.2f * accv[e];
    unsigned short hv = f2bf(a);
    ht[(b_l * 16 + e) * 72 + n_l] = hv;
    if (e < 8) h0[e] = hv; else h1[e - 8] = hv;
  }
  unsigned short* ho = hnc_out + (size_t)(n0 + n_l) * 1024 + c0 + b_l * 16;
  *(ushort8*)(ho)     = h0;
  *(ushort8*)(ho + 8) = h1;
  __syncthreads();

  for (int i = t; i < 512; i += 256) {
    int row = i >> 3, ch = i & 7;
    const unsigned short* s = ht + row * 72 + ch * 8;
    int2 v;
    v.x = pk4_fp8(bf2f(s[0]), bf2f(s[1]), bf2f(s[2]), bf2f(s[3]));
    v.y = pk4_fp8(bf2f(s[4]), bf2f(s[5]), bf2f(s[6]), bf2f(s[7]));
    *(int2*)(hb8 + (size_t)(c0 + row) * 4096 + n0 + ch * 8) = v;
  }
}

__device__ __forceinline__ void linN_tile(const unsigned short* __restrict__ pp,
                                          unsigned short* __restrict__ hnc,
                                          const float* __restrict__ W,
                                          unsigned char* __restrict__ hb8,
                                          int n0, int c0, int t,
                                          unsigned char* sm) {
  float* xs = (float*)sm;
  unsigned short* ht = (unsigned short*)(sm + 16640);

  for (int i = t; i < 512; i += 256) {
    int row = i >> 3, ch = i & 7;
    size_t g = (size_t)(n0 + row) * 1024 + c0 + ch * 8;
    ushort8 a = *(const ushort8*)(pp + g);
    ushort8 b = *(const ushort8*)(pp + P_ELEMS + g);
    ushort8 c = *(const ushort8*)(hnc + g);
    float* dst = xs + row * 65 + ch * 8;
#pragma unroll
    for (int j = 0; j < 8; ++j) dst[j] = bf2f(a[j]) + bf2f(b[j]) + bf2f(c[j]);
  }
  __syncthreads();

  int n_l = t & 63, b_l = t >> 6;
  float xv[16];
#pragma unroll
  for (int d = 0; d < 16; ++d) xv[d] = xs[n_l * 65 + b_l * 16 + d];
  float accv[16];
#pragma unroll
  for (int e = 0; e < 16; ++e) accv[e] = 0.f;
#pragma unroll
  for (int d = 0; d < 16; ++d)
#pragma unroll
    for (int e = 0; e < 16; ++e) accv[e] += xv[d] * W[d * 16 + e];

  ushort8 h0, h1;
#pragma unroll
  for (int e = 0; e < 16; ++e) {
    float a = accv[e] > 0.f ? accv[e] : 0.2f * accv[e];
    unsigned short hv = f2bf(a);
    ht[(b_l * 16 + e) * 72 + n_l] = hv;
    if (e < 8) h0[e] = hv; else h1[e - 8] = hv;
  }
  unsigned short* ho = hnc + (size_t)(n0 + n_l) * 1024 + c0 + b_l * 16;
  *(ushort8*)(ho)     = h0;
  *(ushort8*)(ho + 8) = h1;
  __syncthreads();

  for (int i = t; i < 512; i += 256) {
    int row = i >> 3, ch = i & 7;
    const unsigned short* s = ht + row * 72 + ch * 8;
    int2 v;
    v.x = pk4_fp8(bf2f(s[0]), bf2f(s[1]), bf2f(s[2]), bf2f(s[3]));
    v.y = pk4_fp8(bf2f(s[4]), bf2f(s[5]), bf2f(s[6]), bf2f(s[7]));
    *(int2*)(hb8 + (size_t)(c0 + row) * 4096 + n0 + ch * 8) = v;
  }
}

// ---------------------------------------------------------------------------
// gemm phase (r15's verified 512-thread body).  One K-half per block.
// 8 waves 2(wm) x 4(wn), wave tile 64n x 32c, acc[4][2]; dbuf, XOR chunk
// swizzle, counted vmcnt(4) + raw s_barrier, setprio around MFMA.
// ---------------------------------------------------------------------------
__device__ __forceinline__ void gemm_phase(const unsigned char* __restrict__ A,
                                           const unsigned char* __restrict__ B8,
                                           unsigned short* __restrict__ pp,
                                           unsigned char* sm) {
  const int K = 4096;
  unsigned char* a_s[2] = {sm,         sm + 16384};
  unsigned char* b_s[2] = {sm + 32768, sm + 49152};

  int tid = threadIdx.x, wave = tid >> 6, lane = tid & 63;

  int lin = blockIdx.x;
  int xcd = lin & 7, g = lin >> 3;
  int mth = g & 3, ct = (g >> 2) & 7, ks = g >> 5;   // ks in {0,1}
  int mt = mth * 8 + xcd;
  int n0 = mt * 128, c0 = ct * 128;
  int kbase = ks * 2048;

  int l8 = lane >> 3, lc = lane & 7;
  int swc = lc ^ l8;                 // logical chunk fetched into phys lc
  const unsigned char* gA[2];
  const unsigned char* gB[2];
#pragma unroll
  for (int j = 0; j < 2; ++j) {
    int r = wave * 16 + j * 8 + l8;
    gA[j] = A  + (size_t)(n0 + r) * K + kbase + swc * 16;
    gB[j] = B8 + (size_t)(c0 + r) * K + kbase + swc * 16;
  }

  int i16 = lane & 15, q = lane >> 4;
  int wm = wave >> 2, wn = wave & 3;      // 2 x 4
  int sw7 = i16 & 7;
  int pc0 = ((2 * q) ^ sw7) * 16;
  int pc1 = ((2 * q + 1) ^ sw7) * 16;

#define STAGE(buf, it)                                                \
  do {                                                                \
    int k0_ = (it) * 128;                                             \
    _Pragma("unroll")                                                 \
    for (int j = 0; j < 2; ++j) {                                     \
      GLOAD_LDS16(gA[j] + k0_, a_s[buf] + (wave * 16 + j * 8) * 128); \
      GLOAD_LDS16(gB[j] + k0_, b_s[buf] + (wave * 16 + j * 8) * 128); \
    }                                                                 \
  } while (0)

#define COMPUTE(buf)                                                  \
  do {                                                                \
    i32x8 bv[2];                                                      \
    _Pragma("unroll")                                                 \
    for (int u = 0; u < 2; ++u) {                                     \
      const unsigned char* bp = b_s[buf] + (wn * 32 + u * 16 + i16) * 128; \
      i32x4 blo = *(const i32x4*)(bp + pc0);                          \
      i32x4 bhi = *(const i32x4*)(bp + pc1);                          \
      bv[u] = __builtin_shufflevector(blo, bhi, 0, 1, 2, 3, 4, 5, 6, 7); \
    }                                                                 \
    __builtin_amdgcn_s_setprio(1);                                    \
    _Pragma("unroll")                                                 \
    for (int t = 0; t < 4; ++t) {                                     \
      const unsigned char* ap = a_s[buf] + (wm * 64 + t * 16 + i16) * 128; \
      i32x4 alo = *(const i32x4*)(ap + pc0);                          \
      i32x4 ahi = *(const i32x4*)(ap + pc1);                          \
      i32x8 av = __builtin_shufflevector(alo, ahi, 0, 1, 2, 3, 4, 5, 6, 7); \
      _Pragma("unroll")                                               \
      for (int u = 0; u < 2; ++u)                                     \
        acc[t][u] = __builtin_amdgcn_mfma_scale_f32_16x16x128_f8f6f4( \
            av, bv[u], acc[t][u], 0, 0, 0, SCALE_ONE, 0, SCALE_ONE);  \
    }                                                                 \
    __builtin_amdgcn_s_setprio(0);                                    \
  } while (0)

#define WAITVM4() asm volatile("s_waitcnt vmcnt(4)" ::: "memory")
#define WAITVM0() asm volatile("s_waitcnt vmcnt(0)" ::: "memory")
#define BARX() do { asm volatile("" ::: "memory");                    \
                    __builtin_amdgcn_s_barrier();                     \
                    asm volatile("" ::: "memory"); } while (0)

  f32x4 acc[4][2] = {};

  STAGE(0, 0);
  STAGE(1, 1);

  for (int itb = 0; itb < 14; itb += 2) {
    WAITVM4(); BARX(); COMPUTE(0); BARX(); STAGE(0, itb + 2);
    WAITVM4(); BARX(); COMPUTE(1); BARX(); STAGE(1, itb + 3);
  }
  WAITVM4(); BARX(); COMPUTE(0);           // it = 14
  WAITVM0(); BARX(); COMPUTE(1);           // it = 15

#undef STAGE
#undef COMPUTE
#undef WAITVM4
#undef WAITVM0
#undef BARX

  unsigned short* dst = pp + (size_t)ks * P_ELEMS;
#pragma unroll
  for (int t = 0; t < 4; ++t)
#pragma unroll
    for (int u = 0; u < 2; ++u)
#pragma unroll
      for (int i = 0; i < 4; ++i) {
        int n_g = n0 + wm * 64 + t * 16 + q * 4 + i;
        int c_g = c0 + wn * 32 + u * 16 + i16;
        dst[(size_t)n_g * 1024 + c_g] = f2bf(acc[t][u][i] * ADJ_DESCALE);
      }
}

// ---------------------------------------------------------------------------
// persistent mega-kernel: 512 blocks x 512 threads, exactly 2 blocks/CU
// (64KB static LDS caps at 2; launch_bounds caps VGPR at 128).
// ---------------------------------------------------------------------------
__global__ __launch_bounds__(512, 4)
void gcn_mega(const float* __restrict__ adj, const float* __restrict__ x,
              const float* __restrict__ W0, const float* __restrict__ W1,
              const float* __restrict__ W2,
              unsigned char* __restrict__ adj8, unsigned char* __restrict__ hb8,
              unsigned short* __restrict__ hnc, unsigned short* __restrict__ pp,
              float* __restrict__ out) {
  __shared__ unsigned char smem[65536];
  int bid = blockIdx.x, tid = threadIdx.x;
  unsigned tgt = 512;

  // ---- phase A: adj quantize (grid-stride) + layer-0 linear (2 tiles) ----
#pragma unroll 1
  for (int s = 0; s < 4; ++s) {
    size_t base = ((size_t)(s * 262144 + bid * 512 + tid)) * 16;
    const float4* src = (const float4*)(adj + base);
    float4 q0 = src[0], q1 = src[1], q2 = src[2], q3 = src[3];
    int4 o;
    o.x = pk4_fp8(q0.x * ADJ_SCALE, q0.y * ADJ_SCALE, q0.z * ADJ_SCALE, q0.w * ADJ_SCALE);
    o.y = pk4_fp8(q1.x * ADJ_SCALE, q1.y * ADJ_SCALE, q1.z * ADJ_SCALE, q1.w * ADJ_SCALE);
    o.z = pk4_fp8(q2.x * ADJ_SCALE, q2.y * ADJ_SCALE, q2.z * ADJ_SCALE, q2.w * ADJ_SCALE);
    o.w = pk4_fp8(q3.x * ADJ_SCALE, q3.y * ADJ_SCALE, q3.z * ADJ_SCALE, q3.w * ADJ_SCALE);
    *(int4*)(adj8 + base) = o;
  }
  {
    int h = tid >> 8, t = tid & 255;
    int ti = bid * 2 + h;                       // 0..1023 tiles
    lin0_tile(x, W0, hb8, hnc, (ti & 63) * 64, (ti >> 6) * 64, t,
              smem + h * 32768);
  }
  grid_bar(tgt); tgt += 512;

  // ---- 3 layers ----
#pragma unroll 1
  for (int L = 0; L < 3; ++L) {
    gemm_phase(adj8, hb8, pp, smem);
    grid_bar(tgt); tgt += 512;
    if (L < 2) {
      const float* Wn = (L == 0) ? W1 : W2;
      int h = tid >> 8, t = tid & 255;
      int ti = bid * 2 + h;
      linN_tile(pp, hnc, Wn, hb8, (ti & 63) * 64, (ti >> 6) * 64, t,
                smem + h * 32768);
      grid_bar(tgt); tgt += 512;
    }
  }

  // ---- add_out: out fp32 (b,n,d) = p0 + p1 + hnc ----
#pragma unroll 1
  for (int s = 0; s < 2; ++s) {
    int gid = s * 262144 + bid * 512 + tid;     // 0..524287
    int n = gid >> 7, c8 = (gid & 127) * 8;
    size_t g = (size_t)n * 1024 + c8;
    ushort8 a = *(const ushort8*)(pp + g);
    ushort8 b = *(const ushort8*)(pp + P_ELEMS + g);
    ushort8 hh = *(const ushort8*)(hnc + g);
    float v[8];
#pragma unroll
    for (int j = 0; j < 8; ++j) v[j] = bf2f(a[j]) + bf2f(b[j]) + bf2f(hh[j]);
    int bb = c8 >> 4, d0 = c8 & 15;
    float* o = out + (size_t)bb * 65536 + n * 16 + d0;
    *(float4*)(o)     = float4{v[0], v[1], v[2], v[3]};
    *(float4*)(o + 4) = float4{v[4], v[5], v[6], v[7]};
  }
}

// ---------------------------------------------------------------------------
extern "C" void kernel_launch(void* const* d_in, const int* in_sizes, int n_in,
                              void* d_out, int out_size, void* d_ws, size_t ws_size,
                              hipStream_t stream) {
  const float* x   = (const float*)d_in[0];
  const float* adj = (const float*)d_in[1];
  // d_in[2] = Identity (handled as the +h_nc term)
  const float* W0  = (const float*)d_in[3];
  const float* W1  = (const float*)d_in[4];
  const float* W2  = (const float*)d_in[5];
  float* out = (float*)d_out;

  char* ws = (char*)d_ws;
  unsigned char*  adj8 = (unsigned char*)ws;                   // 16 MiB
  unsigned char*  hb8  = (unsigned char*)(ws + 16777216);      //  4 MiB
  unsigned short* hnc  = (unsigned short*)(ws + 20971520);     //  8 MiB
  unsigned short* pp   = (unsigned short*)(ws + 29360128);     // p0|p1 16 MiB

  // zero the grid-barrier counter (capturable memset node; symbol addr is a
  // plain host-side metadata query, not a stream op)
  void* bar_ptr = nullptr;
  (void)hipGetSymbolAddress(&bar_ptr, HIP_SYMBOL(g_bar));
  (void)hipMemsetAsync(bar_ptr, 0, 64, stream);

  gcn_mega<<<512, 512, 0, stream>>>(adj, x, W0, W1, W2,
                                    adj8, hb8, hnc, pp, out);
}

// Round 12
// 590.228 us; speedup vs baseline: 2.1183x; 2.1183x over previous
//
#include <hip/hip_runtime.h>
#include <stdint.h>

// ---------------------------------------------------------------------------
// GCN block: 3 x [ h = leaky_relu(in @ W);  out = adj@h + h ]   (I folded OUT)
// B=64, N=4096, D=16.  GEMM M=4096 x C=1024 x K=4096 in FP8 e4m3, fp32 accum,
// MX-scaled mfma_scale_16x16x128 with unit scales.
// Round 18: r16 (coop launch) and r17 (persistent + grid barrier: VGPR 64 ->
// scratch spill, 700MB excess traffic, 5x slow) prove grid-wide sync vehicles
// are wrong.  But the linear only needs its OWN 128x128 region's p0+p1 = the
// outputs of 2 SIBLING gemm blocks (ks=0/1, same mt/ct, same XCD).  So:
// pairwise flag handoff inside the gemm launch:
//   both siblings run r15's verbatim K-loop (23us geometry, 2 blocks/CU);
//   election via atomicAdd(&flags[region]): FIRST stores its partial bf16
//   (r15 epilogue) -> threadfence -> +1 -> exit; SECOND spins to base+3
//   (sibling provably mid-flight -> deadlock-free at ANY residency), then
//   u = own_acc*descale + partner_partial + hnc in-thread, and runs the
//   next linear as a tail (r13's verified 512-thr epilogue, LDS reused).
// Launches: memset(flags) + prep + 3x gemm_fused  (was 8 stream ops).
// ws: adj8 16MB | hb8_a 4MB | hb8_b 4MB | hnc 8MB | p 8MB | flags 1KB = 40MB
// ---------------------------------------------------------------------------

typedef float  f32x4  __attribute__((ext_vector_type(4)));
typedef unsigned short ushort8 __attribute__((ext_vector_type(8)));
typedef int    i32x4  __attribute__((ext_vector_type(4)));
typedef int    i32x8  __attribute__((ext_vector_type(8)));

typedef __attribute__((address_space(1))) void* as1p;
typedef __attribute__((address_space(3))) void* as3p;
#define GLOAD_LDS16(G, L) \
  __builtin_amdgcn_global_load_lds((as1p)(G), (as3p)(L), 16, 0, 0)

#define ADJ_SCALE 4096.0f
#define ADJ_DESCALE (1.0f / 4096.0f)
#define SCALE_ONE 0x7f7f7f7f  // e8m0 exponent 127 = 2^0 = 1.0 in every byte

__device__ __forceinline__ unsigned short f2bf(float f) {
  unsigned u = __float_as_uint(f);
  u += 0x7fffu + ((u >> 16) & 1u);  // RNE
  return (unsigned short)(u >> 16);
}
__device__ __forceinline__ float bf2f(unsigned short u) {
  return __uint_as_float(((unsigned)u) << 16);
}
// pack 4 fp32 -> 4 fp8 e4m3 bytes (RNE, saturating)
__device__ __forceinline__ int pk4_fp8(float a, float b, float c, float d) {
  int v = __builtin_amdgcn_cvt_pk_fp8_f32(a, b, 0, false);   // bytes 0,1
  v = __builtin_amdgcn_cvt_pk_fp8_f32(c, d, v, true);        // bytes 2,3
  return v;
}

// ---------------------------------------------------------------------------
// prep: role-split fusion (r12/r15 verbatim, passed).
//   bid <  1024 : layer-0 linear  h0 = leaky(x @ W0), tile 64n x 64c
//   bid >= 1024 : adj8 = e4m3(adj * 4096), 1 thread = 16 elements
// ---------------------------------------------------------------------------
__global__ void prep(const float* __restrict__ adj,
                     unsigned char* __restrict__ a8,
                     const float* __restrict__ x,
                     const float* __restrict__ W,
                     unsigned char* __restrict__ hb8,
                     unsigned short* __restrict__ hnc_out) {
  __shared__ float xs[64 * 65];
  __shared__ unsigned short ht[64 * 72];
  int bid = blockIdx.x;

  if (bid >= 1024) {
    size_t base = ((size_t)(bid - 1024) * 256 + threadIdx.x) * 16;
    const float4* src = (const float4*)(adj + base);
    float4 q0 = src[0], q1 = src[1], q2 = src[2], q3 = src[3];
    int4 o;
    o.x = pk4_fp8(q0.x * ADJ_SCALE, q0.y * ADJ_SCALE, q0.z * ADJ_SCALE, q0.w * ADJ_SCALE);
    o.y = pk4_fp8(q1.x * ADJ_SCALE, q1.y * ADJ_SCALE, q1.z * ADJ_SCALE, q1.w * ADJ_SCALE);
    o.z = pk4_fp8(q2.x * ADJ_SCALE, q2.y * ADJ_SCALE, q2.z * ADJ_SCALE, q2.w * ADJ_SCALE);
    o.w = pk4_fp8(q3.x * ADJ_SCALE, q3.y * ADJ_SCALE, q3.z * ADJ_SCALE, q3.w * ADJ_SCALE);
    *(int4*)(a8 + base) = o;
    return;
  }

  int n0 = (bid & 63) * 64, c0 = (bid >> 6) * 64;

  for (int i = threadIdx.x; i < 1024; i += 256) {
    int bs = i >> 8, rem = i & 255, nr = rem >> 2, d4 = rem & 3;
    float4 v = *(const float4*)(
        x + ((size_t)(c0 / 16 + bs) * 4096 + n0 + nr) * 16 + d4 * 4);
    float* dst = xs + nr * 65 + bs * 16 + d4 * 4;
    dst[0] = v.x; dst[1] = v.y; dst[2] = v.z; dst[3] = v.w;
  }
  __syncthreads();

  int n_l = threadIdx.x & 63, b_l = threadIdx.x >> 6;   // b_l 0..3
  float xv[16];
#pragma unroll
  for (int d = 0; d < 16; ++d) xv[d] = xs[n_l * 65 + b_l * 16 + d];
  float accv[16];
#pragma unroll
  for (int e = 0; e < 16; ++e) accv[e] = 0.f;
#pragma unroll
  for (int d = 0; d < 16; ++d)
#pragma unroll
    for (int e = 0; e < 16; ++e) accv[e] += xv[d] * W[d * 16 + e];

  ushort8 h0, h1;
#pragma unroll
  for (int e = 0; e < 16; ++e) {
    float a = accv[e] > 0.f ? accv[e] : 0.2f * accv[e];
    unsigned short hv = f2bf(a);
    ht[(b_l * 16 + e) * 72 + n_l] = hv;
    if (e < 8) h0[e] = hv; else h1[e - 8] = hv;
  }
  unsigned short* ho = hnc_out + (size_t)(n0 + n_l) * 1024 + c0 + b_l * 16;
  *(ushort8*)(ho)     = h0;
  *(ushort8*)(ho + 8) = h1;
  __syncthreads();

  for (int i = threadIdx.x; i < 512; i += 256) {
    int row = i >> 3, ch = i & 7;
    const unsigned short* s = ht + row * 72 + ch * 8;
    int2 v;
    v.x = pk4_fp8(bf2f(s[0]), bf2f(s[1]), bf2f(s[2]), bf2f(s[3]));
    v.y = pk4_fp8(bf2f(s[4]), bf2f(s[5]), bf2f(s[6]), bf2f(s[7]));
    *(int2*)(hb8 + (size_t)(c0 + row) * 4096 + n0 + ch * 8) = v;
  }
}

// ---------------------------------------------------------------------------
// gemm + pairwise handoff + fused next-layer linear (mode 0) / output (mode 1).
// K-loop: r15's verified 512-thr geometry VERBATIM (ks-split, grid 512 =
// 32mt x 8ct x 2ks, xcd = lin&7, 8 waves 2x4, wave tile 64n x 32c, acc[4][2],
// dbuf, XOR chunk swizzle, counted vmcnt(4) + raw s_barrier, setprio).
// Handoff: region = mt*8+ct; flags[region] starts at `base` (memset once per
// kernel_launch; bases 0/3/6 per layer).  Adds: first-election(+1),
// second-election(+1), first-completion(+1) -> final base+3 always.
//   FIRST  (old==base): store own partial bf16 to p (r15 epilogue form),
//          per-thread threadfence, syncthreads, +1, exit.
//   SECOND (old>base):  tid0 spins to >= base+3 (sibling already elected =>
//          mid-flight => progress guaranteed), fence, then tail:
//   mode 0: u = acc*DESC + bf2f(p) + bf2f(hnc) per fragment -> bf16 deposit
//          into u_bf[128][128] (XOR-16 col swizzle, LDS reused, 32KB) ->
//          r13's verified epilogue: h' = leaky(u@Wn) per 16-group, write
//          hnc (in-place, own region) + ht transposed swizzle -> fp8 hb8o.
//   mode 1: direct f32 scatter  out[(c>>4)*65536 + n*16 + (c&15)] = u.
// ---------------------------------------------------------------------------
__global__ __launch_bounds__(512, 4)
void gemm_fused(const unsigned char* __restrict__ A,
                const unsigned char* __restrict__ B8,
                const float* __restrict__ Wn,
                unsigned short* __restrict__ hnc,
                unsigned char* __restrict__ hb8o,
                unsigned short* __restrict__ p,
                unsigned* __restrict__ flags,
                float* __restrict__ out,
                int base, int mode) {
  const int K = 4096;
  __shared__ unsigned char smem[65536];   // K-loop: A dbuf 32KB | B dbuf 32KB
  __shared__ unsigned who;
  unsigned char* a_s[2] = {smem,         smem + 16384};
  unsigned char* b_s[2] = {smem + 32768, smem + 49152};

  int tid = threadIdx.x, wave = tid >> 6, lane = tid & 63;

  int lin = blockIdx.x;
  int xcd = lin & 7, g = lin >> 3;
  int mth = g & 3, ct = (g >> 2) & 7, ks = g >> 5;   // ks in {0,1}
  int mt = mth * 8 + xcd;
  int n0 = mt * 128, c0 = ct * 128;
  int kbase = ks * 2048;
  int region = mt * 8 + ct;                          // 0..255

  // staging: wave w covers rows w*16..w*16+15 (2 insts each operand)
  int l8 = lane >> 3, lc = lane & 7;
  int swc = lc ^ l8;                 // logical chunk fetched into phys lc
  const unsigned char* gA[2];
  const unsigned char* gB[2];
#pragma unroll
  for (int j = 0; j < 2; ++j) {
    int r = wave * 16 + j * 8 + l8;
    gA[j] = A  + (size_t)(n0 + r) * K + kbase + swc * 16;
    gB[j] = B8 + (size_t)(c0 + r) * K + kbase + swc * 16;
  }

  int i16 = lane & 15, q = lane >> 4;
  int wm = wave >> 2, wn = wave & 3;      // 2 x 4
  int sw7 = i16 & 7;
  int pc0 = ((2 * q) ^ sw7) * 16;
  int pc1 = ((2 * q + 1) ^ sw7) * 16;

#define STAGE(buf, it)                                                \
  do {                                                                \
    int k0_ = (it) * 128;                                             \
    _Pragma("unroll")                                                 \
    for (int j = 0; j < 2; ++j) {                                     \
      GLOAD_LDS16(gA[j] + k0_, a_s[buf] + (wave * 16 + j * 8) * 128); \
      GLOAD_LDS16(gB[j] + k0_, b_s[buf] + (wave * 16 + j * 8) * 128); \
    }                                                                 \
  } while (0)

#define COMPUTE(buf)                                                  \
  do {                                                                \
    i32x8 bv[2];                                                      \
    _Pragma("unroll")                                                 \
    for (int u = 0; u < 2; ++u) {                                     \
      const unsigned char* bp = b_s[buf] + (wn * 32 + u * 16 + i16) * 128; \
      i32x4 blo = *(const i32x4*)(bp + pc0);                          \
      i32x4 bhi = *(const i32x4*)(bp + pc1);                          \
      bv[u] = __builtin_shufflevector(blo, bhi, 0, 1, 2, 3, 4, 5, 6, 7); \
    }                                                                 \
    __builtin_amdgcn_s_setprio(1);                                    \
    _Pragma("unroll")                                                 \
    for (int t = 0; t < 4; ++t) {                                     \
      const unsigned char* ap = a_s[buf] + (wm * 64 + t * 16 + i16) * 128; \
      i32x4 alo = *(const i32x4*)(ap + pc0);                          \
      i32x4 ahi = *(const i32x4*)(ap + pc1);                          \
      i32x8 av = __builtin_shufflevector(alo, ahi, 0, 1, 2, 3, 4, 5, 6, 7); \
      _Pragma("unroll")                                               \
      for (int u = 0; u < 2; ++u)                                     \
        acc[t][u] = __builtin_amdgcn_mfma_scale_f32_16x16x128_f8f6f4( \
            av, bv[u], acc[t][u], 0, 0, 0, SCALE_ONE, 0, SCALE_ONE);  \
    }                                                                 \
    __builtin_amdgcn_s_setprio(0);                                    \
  } while (0)

#define WAITVM4() asm volatile("s_waitcnt vmcnt(4)" ::: "memory")
#define WAITVM0() asm volatile("s_waitcnt vmcnt(0)" ::: "memory")
#define BARX() do { asm volatile("" ::: "memory");                    \
                    __builtin_amdgcn_s_barrier();                     \
                    asm volatile("" ::: "memory"); } while (0)

  f32x4 acc[4][2] = {};

  STAGE(0, 0);
  STAGE(1, 1);

  for (int itb = 0; itb < 14; itb += 2) {
    WAITVM4(); BARX(); COMPUTE(0); BARX(); STAGE(0, itb + 2);
    WAITVM4(); BARX(); COMPUTE(1); BARX(); STAGE(1, itb + 3);
  }
  WAITVM4(); BARX(); COMPUTE(0);           // it = 14
  WAITVM0(); BARX(); COMPUTE(1);           // it = 15

#undef STAGE
#undef COMPUTE
#undef WAITVM4
#undef WAITVM0
#undef BARX

  // ---- election ----
  if (tid == 0) who = atomicAdd(&flags[region], 1u);
  __syncthreads();
  unsigned w = who;

  if (w == (unsigned)base) {
    // FIRST arriver: publish own partial (descaled bf16, r15 epilogue form)
#pragma unroll
    for (int t = 0; t < 4; ++t)
#pragma unroll
      for (int u = 0; u < 2; ++u)
#pragma unroll
        for (int i = 0; i < 4; ++i) {
          int n_g = n0 + wm * 64 + t * 16 + q * 4 + i;
          int c_g = c0 + wn * 32 + u * 16 + i16;
          p[(size_t)n_g * 1024 + c_g] = f2bf(acc[t][u][i] * ADJ_DESCALE);
        }
    __threadfence();
    __syncthreads();
    if (tid == 0) atomicAdd(&flags[region], 1u);
    return;
  }

  // SECOND arriver: wait for sibling's publish (it already elected -> it is
  // mid-flight -> completion guaranteed; no co-residency assumption).
  if (tid == 0) {
    while (__hip_atomic_load(&flags[region], __ATOMIC_ACQUIRE,
                             __HIP_MEMORY_SCOPE_AGENT) < (unsigned)base + 3u)
      __builtin_amdgcn_s_sleep(8);
  }
  __syncthreads();
  __threadfence();

  if (mode == 1) {
    // final layer: direct f32 scatter, u computed fully in-thread
#pragma unroll
    for (int t = 0; t < 4; ++t)
#pragma unroll
      for (int u = 0; u < 2; ++u)
#pragma unroll
        for (int i = 0; i < 4; ++i) {
          int n_l = wm * 64 + t * 16 + q * 4 + i;
          int c_l = wn * 32 + u * 16 + i16;
          size_t gidx = (size_t)(n0 + n_l) * 1024 + c0 + c_l;
          float v = acc[t][u][i] * ADJ_DESCALE + bf2f(p[gidx]) + bf2f(hnc[gidx]);
          int c = c0 + c_l;
          out[(size_t)(c >> 4) * 65536 + (size_t)(n0 + n_l) * 16 + (c & 15)] = v;
        }
    return;
  }

  // mode 0: fused next-layer linear over this 128x128 region.
  unsigned short* u_bf = (unsigned short*)smem;           // 32KB [128][128]
  unsigned short* ht   = (unsigned short*)(smem + 32768); // 32KB [128][128]

  // deposit u (bf16) with XOR-16 column swizzle (r13's scheme)
#pragma unroll
  for (int t = 0; t < 4; ++t)
#pragma unroll
    for (int u = 0; u < 2; ++u)
#pragma unroll
      for (int i = 0; i < 4; ++i) {
        int n_l = wm * 64 + t * 16 + q * 4 + i;
        int c_l = wn * 32 + u * 16 + i16;
        size_t gidx = (size_t)(n0 + n_l) * 1024 + c0 + c_l;
        float uv = acc[t][u][i] * ADJ_DESCALE + bf2f(p[gidx]) + bf2f(hnc[gidx]);
        u_bf[n_l * 128 + (c_l ^ (((n_l >> 2) & 1) << 4))] = f2bf(uv);
      }
  __syncthreads();

  // linear: 1024 (n, group) items, 2 rounds of 512 (r13 epilogue, bf16 src)
  for (int s = 0; s < 2; ++s) {
    int item = s * 512 + tid;
    int n_l = item & 127, gi = item >> 7;      // gi 0..7
    int pg = gi ^ ((n_l >> 2) & 1);
    const unsigned short* up = u_bf + n_l * 128 + pg * 16;
    float ud[16];
#pragma unroll
    for (int d = 0; d < 16; ++d) ud[d] = bf2f(up[d]);
    float hv[16];
#pragma unroll
    for (int e = 0; e < 16; ++e) hv[e] = 0.f;
#pragma unroll
    for (int d = 0; d < 16; ++d)
#pragma unroll
      for (int e = 0; e < 16; ++e) hv[e] += ud[d] * Wn[d * 16 + e];
    ushort8 o0, o1;
#pragma unroll
    for (int e = 0; e < 16; ++e) {
      float a = hv[e] > 0.f ? hv[e] : 0.2f * hv[e];
      unsigned short hb = f2bf(a);
      if (e < 8) o0[e] = hb; else o1[e - 8] = hb;
      int cr = gi * 16 + e;                    // transposed stash, swizzled
      ht[cr * 128 + (((n_l >> 3) ^ (cr & 15)) << 3) + (n_l & 7)] = hb;
    }
    size_t gb = (size_t)(n0 + n_l) * 1024 + c0 + gi * 16;
    *(ushort8*)(hnc + gb)     = o0;            // h' identity term (in-place)
    *(ushort8*)(hnc + gb + 8) = o1;
  }
  __syncthreads();

  // transposed fp8 store: hb8o[c][n]  (r13 epilogue verbatim)
  for (int s = 0; s < 4; ++s) {
    int item = s * 512 + tid;                  // 2048 = 128c x 16 chunks
    int c_l = item >> 4, n8 = item & 15;
    const unsigned short* hp = ht + c_l * 128 + ((n8 ^ (c_l & 15)) << 3);
    int2 v;
    v.x = pk4_fp8(bf2f(hp[0]), bf2f(hp[1]), bf2f(hp[2]), bf2f(hp[3]));
    v.y = pk4_fp8(bf2f(hp[4]), bf2f(hp[5]), bf2f(hp[6]), bf2f(hp[7]));
    *(int2*)(hb8o + (size_t)(c0 + c_l) * 4096 + n0 + n8 * 8) = v;
  }
}

// ---------------------------------------------------------------------------
extern "C" void kernel_launch(void* const* d_in, const int* in_sizes, int n_in,
                              void* d_out, int out_size, void* d_ws, size_t ws_size,
                              hipStream_t stream) {
  const float* x   = (const float*)d_in[0];
  const float* adj = (const float*)d_in[1];
  // d_in[2] = Identity (handled as the +h_nc term)
  const float* W0  = (const float*)d_in[3];
  const float* W1  = (const float*)d_in[4];
  const float* W2  = (const float*)d_in[5];
  float* out = (float*)d_out;

  char* ws = (char*)d_ws;
  unsigned char*  adj8  = (unsigned char*)ws;                  // 16 MiB
  unsigned char*  hb8_a = (unsigned char*)(ws + 16777216);     //  4 MiB
  unsigned char*  hb8_b = (unsigned char*)(ws + 20971520);     //  4 MiB
  unsigned short* hnc   = (unsigned short*)(ws + 25165824);    //  8 MiB
  unsigned short* p     = (unsigned short*)(ws + 33554432);    //  8 MiB
  unsigned*       flags = (unsigned*)(ws + 41943040);          //  1 KiB

  // reset handoff counters (capturable memset; bases 0/3/6 advance per layer)
  (void)hipMemsetAsync(flags, 0, 1024, stream);

  // layer 0 linear + adj quantize fused
  prep<<<5120, 256, 0, stream>>>(adj, adj8, x, W0, hb8_a, hnc);
  // layer 0 gemm + handoff-fused layer-1 linear
  gemm_fused<<<512, 512, 0, stream>>>(adj8, hb8_a, W1, hnc, hb8_b, p, flags,
                                      out, 0, 0);
  // layer 1 gemm + handoff-fused layer-2 linear
  gemm_fused<<<512, 512, 0, stream>>>(adj8, hb8_b, W2, hnc, hb8_a, p, flags,
                                      out, 3, 0);
  // layer 2 gemm + final output
  gemm_fused<<<512, 512, 0, stream>>>(adj8, hb8_a, (const float*)nullptr, hnc,
                                      (unsigned char*)nullptr, p, flags,
                                      out, 6, 1);
}

// Round 13
// 498.096 us; speedup vs baseline: 2.5102x; 1.1850x over previous
//
#include <hip/hip_runtime.h>
#include <stdint.h>

// ---------------------------------------------------------------------------
// GCN block: 3 x [ h = leaky_relu(in @ W);  out = adj@h + h ]   (I folded OUT)
// B=64, N=4096, D=16.  GEMM M=4096 x C=1024 x K=4096 in FP8 e4m3, fp32 accum,
// MX-scaled mfma_scale_16x16x128 with unit scales.
// Round 19 = r18 with the spill fixed.  r18's VGPR=60 (<88 needed) proved
// acc spilled to scratch because it stayed live across the election branch
// and spin-wait -> every MFMA accumulated through scratch (157us).  Fix:
// deposit f2bf(acc*DESC) into LDS u_own[128][128] (32KB, freed by K-loop)
// IMMEDIATELY after the K-loop -> acc dead before election -> no spill.
// Deposit value = exactly the partial-store format, so u = bf16(own) +
// bf16(partner) + bf16(hnc) matches r15's linear_fuse arithmetic bit-for-bit
// (absmax back to 0.03125).
// Handoff protocol (r18, proven correct): flags[region] from `base`
// (memset once; bases 0/3/6): +1 first-elect, +1 second-elect,
// +1 first-complete -> second spins to base+3.  Deadlock-free at any
// residency (sibling provably mid-flight once its election is visible).
// 5 stream ops: memset, prep, 3x gemm_fused  (8-launch fixed-overhead ~140us
// -> ~110us measured across r10/r13/r14/r18 structures).
// ws: adj8 16MB | hb8_a 4MB | hb8_b 4MB | hnc 8MB | p 8MB | flags 1KB = 40MB
// ---------------------------------------------------------------------------

typedef float  f32x4  __attribute__((ext_vector_type(4)));
typedef unsigned short ushort8 __attribute__((ext_vector_type(8)));
typedef int    i32x4  __attribute__((ext_vector_type(4)));
typedef int    i32x8  __attribute__((ext_vector_type(8)));

typedef __attribute__((address_space(1))) void* as1p;
typedef __attribute__((address_space(3))) void* as3p;
#define GLOAD_LDS16(G, L) \
  __builtin_amdgcn_global_load_lds((as1p)(G), (as3p)(L), 16, 0, 0)

#define ADJ_SCALE 4096.0f
#define ADJ_DESCALE (1.0f / 4096.0f)
#define SCALE_ONE 0x7f7f7f7f  // e8m0 exponent 127 = 2^0 = 1.0 in every byte

__device__ __forceinline__ unsigned short f2bf(float f) {
  unsigned u = __float_as_uint(f);
  u += 0x7fffu + ((u >> 16) & 1u);  // RNE
  return (unsigned short)(u >> 16);
}
__device__ __forceinline__ float bf2f(unsigned short u) {
  return __uint_as_float(((unsigned)u) << 16);
}
// pack 4 fp32 -> 4 fp8 e4m3 bytes (RNE, saturating)
__device__ __forceinline__ int pk4_fp8(float a, float b, float c, float d) {
  int v = __builtin_amdgcn_cvt_pk_fp8_f32(a, b, 0, false);   // bytes 0,1
  v = __builtin_amdgcn_cvt_pk_fp8_f32(c, d, v, true);        // bytes 2,3
  return v;
}

// ---------------------------------------------------------------------------
// prep: role-split fusion (r12/r15 verbatim, passed).
//   bid <  1024 : layer-0 linear  h0 = leaky(x @ W0), tile 64n x 64c
//   bid >= 1024 : adj8 = e4m3(adj * 4096), 1 thread = 16 elements
// ---------------------------------------------------------------------------
__global__ void prep(const float* __restrict__ adj,
                     unsigned char* __restrict__ a8,
                     const float* __restrict__ x,
                     const float* __restrict__ W,
                     unsigned char* __restrict__ hb8,
                     unsigned short* __restrict__ hnc_out) {
  __shared__ float xs[64 * 65];
  __shared__ unsigned short ht[64 * 72];
  int bid = blockIdx.x;

  if (bid >= 1024) {
    size_t base = ((size_t)(bid - 1024) * 256 + threadIdx.x) * 16;
    const float4* src = (const float4*)(adj + base);
    float4 q0 = src[0], q1 = src[1], q2 = src[2], q3 = src[3];
    int4 o;
    o.x = pk4_fp8(q0.x * ADJ_SCALE, q0.y * ADJ_SCALE, q0.z * ADJ_SCALE, q0.w * ADJ_SCALE);
    o.y = pk4_fp8(q1.x * ADJ_SCALE, q1.y * ADJ_SCALE, q1.z * ADJ_SCALE, q1.w * ADJ_SCALE);
    o.z = pk4_fp8(q2.x * ADJ_SCALE, q2.y * ADJ_SCALE, q2.z * ADJ_SCALE, q2.w * ADJ_SCALE);
    o.w = pk4_fp8(q3.x * ADJ_SCALE, q3.y * ADJ_SCALE, q3.z * ADJ_SCALE, q3.w * ADJ_SCALE);
    *(int4*)(a8 + base) = o;
    return;
  }

  int n0 = (bid & 63) * 64, c0 = (bid >> 6) * 64;

  for (int i = threadIdx.x; i < 1024; i += 256) {
    int bs = i >> 8, rem = i & 255, nr = rem >> 2, d4 = rem & 3;
    float4 v = *(const float4*)(
        x + ((size_t)(c0 / 16 + bs) * 4096 + n0 + nr) * 16 + d4 * 4);
    float* dst = xs + nr * 65 + bs * 16 + d4 * 4;
    dst[0] = v.x; dst[1] = v.y; dst[2] = v.z; dst[3] = v.w;
  }
  __syncthreads();

  int n_l = threadIdx.x & 63, b_l = threadIdx.x >> 6;   // b_l 0..3
  float xv[16];
#pragma unroll
  for (int d = 0; d < 16; ++d) xv[d] = xs[n_l * 65 + b_l * 16 + d];
  float accv[16];
#pragma unroll
  for (int e = 0; e < 16; ++e) accv[e] = 0.f;
#pragma unroll
  for (int d = 0; d < 16; ++d)
#pragma unroll
    for (int e = 0; e < 16; ++e) accv[e] += xv[d] * W[d * 16 + e];

  ushort8 h0, h1;
#pragma unroll
  for (int e = 0; e < 16; ++e) {
    float a = accv[e] > 0.f ? accv[e] : 0.2f * accv[e];
    unsigned short hv = f2bf(a);
    ht[(b_l * 16 + e) * 72 + n_l] = hv;
    if (e < 8) h0[e] = hv; else h1[e - 8] = hv;
  }
  unsigned short* ho = hnc_out + (size_t)(n0 + n_l) * 1024 + c0 + b_l * 16;
  *(ushort8*)(ho)     = h0;
  *(ushort8*)(ho + 8) = h1;
  __syncthreads();

  for (int i = threadIdx.x; i < 512; i += 256) {
    int row = i >> 3, ch = i & 7;
    const unsigned short* s = ht + row * 72 + ch * 8;
    int2 v;
    v.x = pk4_fp8(bf2f(s[0]), bf2f(s[1]), bf2f(s[2]), bf2f(s[3]));
    v.y = pk4_fp8(bf2f(s[4]), bf2f(s[5]), bf2f(s[6]), bf2f(s[7]));
    *(int2*)(hb8 + (size_t)(c0 + row) * 4096 + n0 + ch * 8) = v;
  }
}

// ---------------------------------------------------------------------------
// gemm + pairwise handoff + fused next-layer linear (mode 0) / output (mode 1).
// K-loop: r15's verified geometry VERBATIM.  After the loop the accumulator
// is IMMEDIATELY deposited to LDS as bf16 partials (acc dies -> no spill),
// then election / handoff / epilogue run from LDS.
// ---------------------------------------------------------------------------
__global__ __launch_bounds__(512, 4)
void gemm_fused(const unsigned char* __restrict__ A,
                const unsigned char* __restrict__ B8,
                const float* __restrict__ Wn,
                unsigned short* __restrict__ hnc,
                unsigned char* __restrict__ hb8o,
                unsigned short* __restrict__ p,
                unsigned* __restrict__ flags,
                float* __restrict__ out,
                int base, int mode) {
  const int K = 4096;
  __shared__ unsigned char smem[65536];   // K-loop: A dbuf 32KB | B dbuf 32KB
  __shared__ unsigned who;
  unsigned char* a_s[2] = {smem,         smem + 16384};
  unsigned char* b_s[2] = {smem + 32768, smem + 49152};

  int tid = threadIdx.x, wave = tid >> 6, lane = tid & 63;

  int lin = blockIdx.x;
  int xcd = lin & 7, g = lin >> 3;
  int mth = g & 3, ct = (g >> 2) & 7, ks = g >> 5;   // ks in {0,1}
  int mt = mth * 8 + xcd;
  int n0 = mt * 128, c0 = ct * 128;
  int kbase = ks * 2048;
  int region = mt * 8 + ct;                          // 0..255

  int l8 = lane >> 3, lc = lane & 7;
  int swc = lc ^ l8;                 // logical chunk fetched into phys lc
  const unsigned char* gA[2];
  const unsigned char* gB[2];
#pragma unroll
  for (int j = 0; j < 2; ++j) {
    int r = wave * 16 + j * 8 + l8;
    gA[j] = A  + (size_t)(n0 + r) * K + kbase + swc * 16;
    gB[j] = B8 + (size_t)(c0 + r) * K + kbase + swc * 16;
  }

  int i16 = lane & 15, q = lane >> 4;
  int wm = wave >> 2, wn = wave & 3;      // 2 x 4
  int sw7 = i16 & 7;
  int pc0 = ((2 * q) ^ sw7) * 16;
  int pc1 = ((2 * q + 1) ^ sw7) * 16;

#define STAGE(buf, it)                                                \
  do {                                                                \
    int k0_ = (it) * 128;                                             \
    _Pragma("unroll")                                                 \
    for (int j = 0; j < 2; ++j) {                                     \
      GLOAD_LDS16(gA[j] + k0_, a_s[buf] + (wave * 16 + j * 8) * 128); \
      GLOAD_LDS16(gB[j] + k0_, b_s[buf] + (wave * 16 + j * 8) * 128); \
    }                                                                 \
  } while (0)

#define COMPUTE(buf)                                                  \
  do {                                                                \
    i32x8 bv[2];                                                      \
    _Pragma("unroll")                                                 \
    for (int u = 0; u < 2; ++u) {                                     \
      const unsigned char* bp = b_s[buf] + (wn * 32 + u * 16 + i16) * 128; \
      i32x4 blo = *(const i32x4*)(bp + pc0);                          \
      i32x4 bhi = *(const i32x4*)(bp + pc1);                          \
      bv[u] = __builtin_shufflevector(blo, bhi, 0, 1, 2, 3, 4, 5, 6, 7); \
    }                                                                 \
    __builtin_amdgcn_s_setprio(1);                                    \
    _Pragma("unroll")                                                 \
    for (int t = 0; t < 4; ++t) {                                     \
      const unsigned char* ap = a_s[buf] + (wm * 64 + t * 16 + i16) * 128; \
      i32x4 alo = *(const i32x4*)(ap + pc0);                          \
      i32x4 ahi = *(const i32x4*)(ap + pc1);                          \
      i32x8 av = __builtin_shufflevector(alo, ahi, 0, 1, 2, 3, 4, 5, 6, 7); \
      _Pragma("unroll")                                               \
      for (int u = 0; u < 2; ++u)                                     \
        acc[t][u] = __builtin_amdgcn_mfma_scale_f32_16x16x128_f8f6f4( \
            av, bv[u], acc[t][u], 0, 0, 0, SCALE_ONE, 0, SCALE_ONE);  \
    }                                                                 \
    __builtin_amdgcn_s_setprio(0);                                    \
  } while (0)

#define WAITVM4() asm volatile("s_waitcnt vmcnt(4)" ::: "memory")
#define WAITVM0() asm volatile("s_waitcnt vmcnt(0)" ::: "memory")
#define BARX() do { asm volatile("" ::: "memory");                    \
                    __builtin_amdgcn_s_barrier();                     \
                    asm volatile("" ::: "memory"); } while (0)

  f32x4 acc[4][2] = {};

  STAGE(0, 0);
  STAGE(1, 1);

  for (int itb = 0; itb < 14; itb += 2) {
    WAITVM4(); BARX(); COMPUTE(0); BARX(); STAGE(0, itb + 2);
    WAITVM4(); BARX(); COMPUTE(1); BARX(); STAGE(1, itb + 3);
  }
  WAITVM4(); BARX(); COMPUTE(0);           // it = 14
  WAITVM0(); BARX(); COMPUTE(1);           // it = 15

#undef STAGE
#undef COMPUTE
#undef WAITVM4
#undef WAITVM0
#undef BARX

  // ---- deposit own partial to LDS (bf16, partial-store format) ----------
  // acc DIES here -> no live range across election/spin -> no spill.
  unsigned short* u_own = (unsigned short*)smem;           // 32KB [128][128]
  unsigned short* ht    = (unsigned short*)(smem + 32768); // 32KB (mode 0)
  __syncthreads();                        // all K-loop LDS reads done
#pragma unroll
  for (int t = 0; t < 4; ++t)
#pragma unroll
    for (int u = 0; u < 2; ++u)
#pragma unroll
      for (int i = 0; i < 4; ++i) {
        int n_l = wm * 64 + t * 16 + q * 4 + i;
        int c_l = wn * 32 + u * 16 + i16;
        u_own[n_l * 128 + (c_l ^ (((n_l >> 2) & 1) << 4))] =
            f2bf(acc[t][u][i] * ADJ_DESCALE);
      }
  __syncthreads();

  // ---- election ----
  if (tid == 0) who = atomicAdd(&flags[region], 1u);
  __syncthreads();
  unsigned w = who;

  if (w == (unsigned)base) {
    // FIRST arriver: copy LDS partial -> p (de-swizzled, coalesced), exit.
    for (int s = 0; s < 2; ++s) {
      int item = s * 512 + tid;                 // 1024 = 128 rows x 8 groups
      int n_l = item & 127, cg = item >> 7;     // cg 0..7
      int pgc = cg ^ ((n_l >> 2) & 1);
      const ushort8* src = (const ushort8*)(u_own + n_l * 128 + pgc * 16);
      unsigned short* dp = p + (size_t)(n0 + n_l) * 1024 + c0 + cg * 16;
      *(ushort8*)(dp)     = src[0];
      *(ushort8*)(dp + 8) = src[1];
    }
    __threadfence();
    __syncthreads();
    if (tid == 0) atomicAdd(&flags[region], 1u);
    return;
  }

  // SECOND arriver: wait for sibling's publish (sibling already elected ->
  // mid-flight -> progress guaranteed; no co-residency assumption).
  if (tid == 0) {
    while (__hip_atomic_load(&flags[region], __ATOMIC_ACQUIRE,
                             __HIP_MEMORY_SCOPE_AGENT) < (unsigned)base + 3u)
      __builtin_amdgcn_s_sleep(8);
    __threadfence();
  }
  __syncthreads();

  if (mode == 1) {
    // final layer: out fp32 (b,n,d) = own + partner + hnc
    for (int s = 0; s < 2; ++s) {
      int item = s * 512 + tid;
      int n_l = item & 127, cg = item >> 7;     // cg 0..7
      int pgc = cg ^ ((n_l >> 2) & 1);
      const unsigned short* up = u_own + n_l * 128 + pgc * 16;
      size_t gb = (size_t)(n0 + n_l) * 1024 + c0 + cg * 16;
      ushort8 p0 = *(const ushort8*)(p + gb);
      ushort8 p1 = *(const ushort8*)(p + gb + 8);
      ushort8 h0 = *(const ushort8*)(hnc + gb);
      ushort8 h1 = *(const ushort8*)(hnc + gb + 8);
      float v[16];
#pragma unroll
      for (int d = 0; d < 8; ++d) {
        v[d]     = bf2f(up[d])     + bf2f(p0[d]) + bf2f(h0[d]);
        v[d + 8] = bf2f(up[d + 8]) + bf2f(p1[d]) + bf2f(h1[d]);
      }
      int bb = (c0 >> 4) + cg;
      float* op = out + (size_t)bb * 65536 + (size_t)(n0 + n_l) * 16;
      *(float4*)(op)      = float4{v[0],  v[1],  v[2],  v[3]};
      *(float4*)(op + 4)  = float4{v[4],  v[5],  v[6],  v[7]};
      *(float4*)(op + 8)  = float4{v[8],  v[9],  v[10], v[11]};
      *(float4*)(op + 12) = float4{v[12], v[13], v[14], v[15]};
    }
    return;
  }

  // mode 0: fused next-layer linear over this 128x128 region.
  // u = bf16(own) + bf16(partner) + bf16(hnc)  -- identical arithmetic to
  // r15's linear_fuse (all three terms bf16).
  for (int s = 0; s < 2; ++s) {
    int item = s * 512 + tid;
    int n_l = item & 127, gi = item >> 7;      // gi 0..7
    int pg = gi ^ ((n_l >> 2) & 1);
    const unsigned short* up = u_own + n_l * 128 + pg * 16;
    size_t gb = (size_t)(n0 + n_l) * 1024 + c0 + gi * 16;
    ushort8 p0 = *(const ushort8*)(p + gb);
    ushort8 p1 = *(const ushort8*)(p + gb + 8);
    ushort8 h0 = *(const ushort8*)(hnc + gb);
    ushort8 h1 = *(const ushort8*)(hnc + gb + 8);
    float ud[16];
#pragma unroll
    for (int d = 0; d < 8; ++d) {
      ud[d]     = bf2f(up[d])     + bf2f(p0[d]) + bf2f(h0[d]);
      ud[d + 8] = bf2f(up[d + 8]) + bf2f(p1[d]) + bf2f(h1[d]);
    }
    float hv[16];
#pragma unroll
    for (int e = 0; e < 16; ++e) hv[e] = 0.f;
#pragma unroll
    for (int d = 0; d < 16; ++d)
#pragma unroll
      for (int e = 0; e < 16; ++e) hv[e] += ud[d] * Wn[d * 16 + e];
    ushort8 o0, o1;
#pragma unroll
    for (int e = 0; e < 16; ++e) {
      float a = hv[e] > 0.f ? hv[e] : 0.2f * hv[e];
      unsigned short hb = f2bf(a);
      if (e < 8) o0[e] = hb; else o1[e - 8] = hb;
      int cr = gi * 16 + e;                    // transposed stash, swizzled
      ht[cr * 128 + (((n_l >> 3) ^ (cr & 15)) << 3) + (n_l & 7)] = hb;
    }
    *(ushort8*)(hnc + gb)     = o0;            // h' identity term (in-place)
    *(ushort8*)(hnc + gb + 8) = o1;
  }
  __syncthreads();

  // transposed fp8 store: hb8o[c][n]  (r13 epilogue verbatim)
  for (int s = 0; s < 4; ++s) {
    int item = s * 512 + tid;                  // 2048 = 128c x 16 chunks
    int c_l = item >> 4, n8 = item & 15;
    const unsigned short* hp = ht + c_l * 128 + ((n8 ^ (c_l & 15)) << 3);
    int2 v;
    v.x = pk4_fp8(bf2f(hp[0]), bf2f(hp[1]), bf2f(hp[2]), bf2f(hp[3]));
    v.y = pk4_fp8(bf2f(hp[4]), bf2f(hp[5]), bf2f(hp[6]), bf2f(hp[7]));
    *(int2*)(hb8o + (size_t)(c0 + c_l) * 4096 + n0 + n8 * 8) = v;
  }
}

// ---------------------------------------------------------------------------
extern "C" void kernel_launch(void* const* d_in, const int* in_sizes, int n_in,
                              void* d_out, int out_size, void* d_ws, size_t ws_size,
                              hipStream_t stream) {
  const float* x   = (const float*)d_in[0];
  const float* adj = (const float*)d_in[1];
  // d_in[2] = Identity (handled as the +h_nc term)
  const float* W0  = (const float*)d_in[3];
  const float* W1  = (const float*)d_in[4];
  const float* W2  = (const float*)d_in[5];
  float* out = (float*)d_out;

  char* ws = (char*)d_ws;
  unsigned char*  adj8  = (unsigned char*)ws;                  // 16 MiB
  unsigned char*  hb8_a = (unsigned char*)(ws + 16777216);     //  4 MiB
  unsigned char*  hb8_b = (unsigned char*)(ws + 20971520);     //  4 MiB
  unsigned short* hnc   = (unsigned short*)(ws + 25165824);    //  8 MiB
  unsigned short* p     = (unsigned short*)(ws + 33554432);    //  8 MiB
  unsigned*       flags = (unsigned*)(ws + 41943040);          //  1 KiB

  // reset handoff counters (capturable memset; bases 0/3/6 advance per layer)
  (void)hipMemsetAsync(flags, 0, 1024, stream);

  // layer 0 linear + adj quantize fused
  prep<<<5120, 256, 0, stream>>>(adj, adj8, x, W0, hb8_a, hnc);
  // layer 0 gemm + handoff-fused layer-1 linear
  gemm_fused<<<512, 512, 0, stream>>>(adj8, hb8_a, W1, hnc, hb8_b, p, flags,
                                      out, 0, 0);
  // layer 1 gemm + handoff-fused layer-2 linear
  gemm_fused<<<512, 512, 0, stream>>>(adj8, hb8_b, W2, hnc, hb8_a, p, flags,
                                      out, 3, 0);
  // layer 2 gemm + final output
  gemm_fused<<<512, 512, 0, stream>>>(adj8, hb8_a, (const float*)nullptr, hnc,
                                      (unsigned char*)nullptr, p, flags,
                                      out, 6, 1);
}

// Round 14
// 245.686 us; speedup vs baseline: 5.0890x; 2.0274x over previous
//
#include <hip/hip_runtime.h>
#include <stdint.h>

// ---------------------------------------------------------------------------
// GCN block: 3 x [ h = leaky_relu(in @ W);  out = adj@h + h ]   (I folded OUT)
// B=64, N=4096, D=16.  GEMM M=4096 x C=1024 x K=4096 in FP8 e4m3, fp32 accum,
// MX-scaled mfma_scale_16x16x128 with unit scales.
// Round 20: in-kernel handoff family closed (r17/r18/r19: codegen spill +
// fence storms, ~100us/gemm pathology).  Back to the surviving law:
//   gemm = block-iters/CU x ~1500cyc (2 blocks/CU), schedule-insensitive.
// Change the COUNT, not the schedule: BK=256 single-buffered.
//   128^2 ks-split tile, 8 iters (was 16), LDS A 32KB + B 32KB = 64KB/block
//   -> still 2 blocks/CU.  Per-iter convoy carries 2x compute (32 MFMA/wave)
//   but there are half as many: 16 block-iters/CU x ~1650cyc ~= 11us/gemm.
//   LDS-port floor agrees: 192KB/block-iter / 128B/cyc = 1500cyc.
// Staging: pre-swizzled global source, XOR chunk swizzle per 128B half
//   (phys = logical ^ (row&7) within each half) -> read offsets pc0/pc1
//   unchanged from r7/r15; MFMA math bit-identical.  Sync = r9-proven
//   two-__syncthreads drain (law says schedule doesn't matter; use safest).
// prep / linear_fuse / add_out / launcher: r12/r15 verbatim (passed).
// ws: adj8 16MB | hb8 4MB | h_nc 8MB | p0 8MB | p1 8MB = 44MB
// ---------------------------------------------------------------------------

typedef float  f32x4  __attribute__((ext_vector_type(4)));
typedef unsigned short ushort8 __attribute__((ext_vector_type(8)));
typedef int    i32x4  __attribute__((ext_vector_type(4)));
typedef int    i32x8  __attribute__((ext_vector_type(8)));

typedef __attribute__((address_space(1))) void* as1p;
typedef __attribute__((address_space(3))) void* as3p;
#define GLOAD_LDS16(G, L) \
  __builtin_amdgcn_global_load_lds((as1p)(G), (as3p)(L), 16, 0, 0)

#define P_ELEMS 4194304       // elems per partial buffer (4096*1024)
#define ADJ_SCALE 4096.0f
#define ADJ_DESCALE (1.0f / 4096.0f)
#define SCALE_ONE 0x7f7f7f7f  // e8m0 exponent 127 = 2^0 = 1.0 in every byte

__device__ __forceinline__ unsigned short f2bf(float f) {
  unsigned u = __float_as_uint(f);
  u += 0x7fffu + ((u >> 16) & 1u);  // RNE
  return (unsigned short)(u >> 16);
}
__device__ __forceinline__ float bf2f(unsigned short u) {
  return __uint_as_float(((unsigned)u) << 16);
}
// pack 4 fp32 -> 4 fp8 e4m3 bytes (RNE, saturating)
__device__ __forceinline__ int pk4_fp8(float a, float b, float c, float d) {
  int v = __builtin_amdgcn_cvt_pk_fp8_f32(a, b, 0, false);   // bytes 0,1
  v = __builtin_amdgcn_cvt_pk_fp8_f32(c, d, v, true);        // bytes 2,3
  return v;
}

// ---------------------------------------------------------------------------
// prep: role-split fusion of two independent memory-bound kernels.
//   bid <  1024 : layer-0 linear  h0 = leaky(x @ W0), tile 64n x 64c
//   bid >= 1024 : adj8 = e4m3(adj * 4096), 1 thread = 16 elements
// ---------------------------------------------------------------------------
__global__ void prep(const float* __restrict__ adj,
                     unsigned char* __restrict__ a8,
                     const float* __restrict__ x,
                     const float* __restrict__ W,
                     unsigned char* __restrict__ hb8,
                     unsigned short* __restrict__ hnc_out) {
  __shared__ float xs[64 * 65];
  __shared__ unsigned short ht[64 * 72];
  int bid = blockIdx.x;

  if (bid >= 1024) {
    size_t base = ((size_t)(bid - 1024) * 256 + threadIdx.x) * 16;
    const float4* src = (const float4*)(adj + base);
    float4 q0 = src[0], q1 = src[1], q2 = src[2], q3 = src[3];
    int4 o;
    o.x = pk4_fp8(q0.x * ADJ_SCALE, q0.y * ADJ_SCALE, q0.z * ADJ_SCALE, q0.w * ADJ_SCALE);
    o.y = pk4_fp8(q1.x * ADJ_SCALE, q1.y * ADJ_SCALE, q1.z * ADJ_SCALE, q1.w * ADJ_SCALE);
    o.z = pk4_fp8(q2.x * ADJ_SCALE, q2.y * ADJ_SCALE, q2.z * ADJ_SCALE, q2.w * ADJ_SCALE);
    o.w = pk4_fp8(q3.x * ADJ_SCALE, q3.y * ADJ_SCALE, q3.z * ADJ_SCALE, q3.w * ADJ_SCALE);
    *(int4*)(a8 + base) = o;
    return;
  }

  int n0 = (bid & 63) * 64, c0 = (bid >> 6) * 64;

  for (int i = threadIdx.x; i < 1024; i += 256) {
    int bs = i >> 8, rem = i & 255, nr = rem >> 2, d4 = rem & 3;
    float4 v = *(const float4*)(
        x + ((size_t)(c0 / 16 + bs) * 4096 + n0 + nr) * 16 + d4 * 4);
    float* dst = xs + nr * 65 + bs * 16 + d4 * 4;
    dst[0] = v.x; dst[1] = v.y; dst[2] = v.z; dst[3] = v.w;
  }
  __syncthreads();

  int n_l = threadIdx.x & 63, b_l = threadIdx.x >> 6;   // b_l 0..3
  float xv[16];
#pragma unroll
  for (int d = 0; d < 16; ++d) xv[d] = xs[n_l * 65 + b_l * 16 + d];
  float accv[16];
#pragma unroll
  for (int e = 0; e < 16; ++e) accv[e] = 0.f;
#pragma unroll
  for (int d = 0; d < 16; ++d)
#pragma unroll
    for (int e = 0; e < 16; ++e) accv[e] += xv[d] * W[d * 16 + e];

  ushort8 h0, h1;
#pragma unroll
  for (int e = 0; e < 16; ++e) {
    float a = accv[e] > 0.f ? accv[e] : 0.2f * accv[e];
    unsigned short hv = f2bf(a);
    ht[(b_l * 16 + e) * 72 + n_l] = hv;
    if (e < 8) h0[e] = hv; else h1[e - 8] = hv;
  }
  unsigned short* ho = hnc_out + (size_t)(n0 + n_l) * 1024 + c0 + b_l * 16;
  *(ushort8*)(ho)     = h0;
  *(ushort8*)(ho + 8) = h1;
  __syncthreads();

  for (int i = threadIdx.x; i < 512; i += 256) {
    int row = i >> 3, ch = i & 7;
    const unsigned short* s = ht + row * 72 + ch * 8;
    int2 v;
    v.x = pk4_fp8(bf2f(s[0]), bf2f(s[1]), bf2f(s[2]), bf2f(s[3]));
    v.y = pk4_fp8(bf2f(s[4]), bf2f(s[5]), bf2f(s[6]), bf2f(s[7]));
    *(int2*)(hb8 + (size_t)(c0 + row) * 4096 + n0 + ch * 8) = v;
  }
}

// ---------------------------------------------------------------------------
// linear layers 1,2: u = p0 + p1 + h_nc (bf16); h = leaky_relu(u @ W);
// writes hb8 fp8 [c][n] (GEMM B operand, via LDS transpose) and h_nc bf16
// [n][c] (identity term for consumers).  Tile 64n x 64c, grid (64,16).
// ---------------------------------------------------------------------------
__global__ void linear_fuse(const unsigned short* __restrict__ pp,
                            const unsigned short* __restrict__ hnc_in,
                            const float* __restrict__ W,
                            unsigned char* __restrict__ hb8,
                            unsigned short* __restrict__ hnc_out) {
  __shared__ float xs[64 * 65];
  __shared__ unsigned short ht[64 * 72];
  int n0 = blockIdx.x * 64, c0 = blockIdx.y * 64;

  for (int i = threadIdx.x; i < 512; i += 256) {
    int row = i >> 3, ch = i & 7;
    size_t g = (size_t)(n0 + row) * 1024 + c0 + ch * 8;
    ushort8 a = *(const ushort8*)(pp + g);
    ushort8 b = *(const ushort8*)(pp + P_ELEMS + g);
    ushort8 c = *(const ushort8*)(hnc_in + g);
    float* dst = xs + row * 65 + ch * 8;
#pragma unroll
    for (int j = 0; j < 8; ++j) dst[j] = bf2f(a[j]) + bf2f(b[j]) + bf2f(c[j]);
  }
  __syncthreads();

  int n_l = threadIdx.x & 63, b_l = threadIdx.x >> 6;
  float xv[16];
#pragma unroll
  for (int d = 0; d < 16; ++d) xv[d] = xs[n_l * 65 + b_l * 16 + d];
  float accv[16];
#pragma unroll
  for (int e = 0; e < 16; ++e) accv[e] = 0.f;
#pragma unroll
  for (int d = 0; d < 16; ++d)
#pragma unroll
    for (int e = 0; e < 16; ++e) accv[e] += xv[d] * W[d * 16 + e];

  ushort8 h0, h1;
#pragma unroll
  for (int e = 0; e < 16; ++e) {
    float a = accv[e] > 0.f ? accv[e] : 0.2f * accv[e];
    unsigned short hv = f2bf(a);
    ht[(b_l * 16 + e) * 72 + n_l] = hv;
    if (e < 8) h0[e] = hv; else h1[e - 8] = hv;
  }
  unsigned short* ho = hnc_out + (size_t)(n0 + n_l) * 1024 + c0 + b_l * 16;
  *(ushort8*)(ho)     = h0;
  *(ushort8*)(ho + 8) = h1;
  __syncthreads();

  for (int i = threadIdx.x; i < 512; i += 256) {
    int row = i >> 3, ch = i & 7;
    const unsigned short* s = ht + row * 72 + ch * 8;
    int2 v;
    v.x = pk4_fp8(bf2f(s[0]), bf2f(s[1]), bf2f(s[2]), bf2f(s[3]));
    v.y = pk4_fp8(bf2f(s[4]), bf2f(s[5]), bf2f(s[6]), bf2f(s[7]));
    *(int2*)(hb8 + (size_t)(c0 + row) * 4096 + n0 + ch * 8) = v;
  }
}

// ---------------------------------------------------------------------------
// final: out fp32 (b,n,d) = p0 + p1 + h_nc   (all stored [n][c] bf16)
// ---------------------------------------------------------------------------
__global__ void add_out(const unsigned short* __restrict__ pp,
                        const unsigned short* __restrict__ hnc,
                        float* __restrict__ out) {
  int gid = blockIdx.x * 256 + threadIdx.x;      // 0..524287
  int n = gid >> 7, c8 = (gid & 127) * 8;
  size_t g = (size_t)n * 1024 + c8;
  ushort8 a = *(const ushort8*)(pp + g);
  ushort8 b = *(const ushort8*)(pp + P_ELEMS + g);
  ushort8 h = *(const ushort8*)(hnc + g);
  float v[8];
#pragma unroll
  for (int j = 0; j < 8; ++j) v[j] = bf2f(a[j]) + bf2f(b[j]) + bf2f(h[j]);
  int bb = c8 >> 4, d0 = c8 & 15;                // d0 = 0 or 8
  float* o = out + (size_t)bb * 65536 + n * 16 + d0;
  *(float4*)(o)     = float4{v[0], v[1], v[2], v[3]};
  *(float4*)(o + 4) = float4{v[4], v[5], v[6], v[7]};
}

// ---------------------------------------------------------------------------
// p[ks][n][c] = (adj8[n0..][k] * hb8[c0..][k]) / 4096   (one K-half per block)
// MX-scaled fp8 MFMA 16x16x128, unit scales.  Grid 512 = 32mt x 8ct x 2ks,
// xcd = lin&7.  256 thr, 4 waves 2x2, wave tile 64x64, acc[4][4] (r7 form).
// BK=256, SINGLE buffer: 8 iters/block (16 block-iters/CU, half of r15).
// LDS rows are 256B = two 128B halves; within each half, XOR chunk swizzle
// phys = logical ^ (row&7) (pre-swizzled global source).  Read offsets
// pc0/pc1 identical to r7; MFMA sequence bit-identical (just 2 k-sub passes
// per iter instead of 2 iters).  Per iter per wave: 16 gload_lds (A 8, B 8),
// 32 ds_read_b128, 32 MFMA.  Sync: STAGE -> __syncthreads (vmcnt0 drain,
// tile visible) -> COMPUTE -> __syncthreads (reads done before overwrite).
// The co-resident block hides the drain (proven 2.1x overlap, r7..r15).
// ---------------------------------------------------------------------------
__global__ __launch_bounds__(256, 2)
void gemm_f8(const unsigned char* __restrict__ A,
             const unsigned char* __restrict__ B8,
             unsigned short* __restrict__ pp) {
  const int K = 4096;
  __shared__ unsigned char a_s[128 * 256];   // 32 KB
  __shared__ unsigned char b_s[128 * 256];   // 32 KB

  int tid = threadIdx.x, wave = tid >> 6, lane = tid & 63;

  int lin = blockIdx.x;
  int xcd = lin & 7, g = lin >> 3;
  int mth = g & 3, ct = (g >> 2) & 7, ks = g >> 5;   // ks in {0,1}
  int mt = mth * 8 + xcd;
  int n0 = mt * 128, c0 = ct * 128;
  int kbase = ks * 2048;

  // staging lane mapping: inst j covers rows (wave*32 + j*4)..+3, 16 chunks.
  // lane -> row_sub = lane>>4 (0..3), phys chunk p15 = lane&15.
  // phys p15 = half*8 + pc7 holds logical chunk half*8 + (pc7 ^ (row&7)).
  // row&7 = (j&1)*4 + row_sub  (wave*32 and j*8-steps are 0 mod 8).
  int l16 = lane >> 4, p15 = lane & 15;
  int half = p15 >> 3, pc7 = p15 & 7;
  int ko0 = (half * 8 + (pc7 ^ l16)) * 16;          // j even: row&7 = l16
  int ko1 = (half * 8 + (pc7 ^ (4 + l16))) * 16;    // j odd:  row&7 = 4+l16
  const unsigned char* pA[2];
  const unsigned char* pB[2];
  pA[0] = A  + (size_t)(n0 + wave * 32 + l16) * K + kbase + ko0;
  pA[1] = A  + (size_t)(n0 + wave * 32 + 4 + l16) * K + kbase + ko1;
  pB[0] = B8 + (size_t)(c0 + wave * 32 + l16) * K + kbase + ko0;
  pB[1] = B8 + (size_t)(c0 + wave * 32 + 4 + l16) * K + kbase + ko1;

  int i16 = lane & 15, q = lane >> 4;
  int wm = wave >> 1, wn = wave & 1;
  int sw7 = i16 & 7;
  int pc0 = ((2 * q) ^ sw7) * 16;        // phys offset of logical chunk 2q
  int pc1 = ((2 * q + 1) ^ sw7) * 16;    // phys offset of logical chunk 2q+1

#define STAGE(it)                                                     \
  do {                                                                \
    int k0_ = (it) * 256;                                             \
    _Pragma("unroll")                                                 \
    for (int j = 0; j < 8; ++j) {                                     \
      GLOAD_LDS16(pA[j & 1] + (size_t)(j >> 1) * 8 * K + k0_,         \
                  a_s + wave * 8192 + j * 1024);                      \
      GLOAD_LDS16(pB[j & 1] + (size_t)(j >> 1) * 8 * K + k0_,         \
                  b_s + wave * 8192 + j * 1024);                      \
    }                                                                 \
  } while (0)

#define COMPUTE()                                                     \
  do {                                                                \
    _Pragma("unroll")                                                 \
    for (int s01 = 0; s01 < 2; ++s01) {                               \
      int sb = s01 * 128;                                             \
      i32x8 bv[4];                                                    \
      _Pragma("unroll")                                               \
      for (int u = 0; u < 4; ++u) {                                   \
        const unsigned char* bp =                                     \
            b_s + (wn * 64 + u * 16 + i16) * 256 + sb;                \
        i32x4 blo = *(const i32x4*)(bp + pc0);                        \
        i32x4 bhi = *(const i32x4*)(bp + pc1);                        \
        bv[u] = __builtin_shufflevector(blo, bhi, 0, 1, 2, 3, 4, 5, 6, 7); \
      }                                                               \
      __builtin_amdgcn_s_setprio(1);                                  \
      _Pragma("unroll")                                               \
      for (int t = 0; t < 4; ++t) {                                   \
        const unsigned char* ap =                                     \
            a_s + (wm * 64 + t * 16 + i16) * 256 + sb;                \
        i32x4 alo = *(const i32x4*)(ap + pc0);                        \
        i32x4 ahi = *(const i32x4*)(ap + pc1);                        \
        i32x8 av = __builtin_shufflevector(alo, ahi, 0, 1, 2, 3, 4, 5, 6, 7); \
        _Pragma("unroll")                                             \
        for (int u = 0; u < 4; ++u)                                   \
          acc[t][u] = __builtin_amdgcn_mfma_scale_f32_16x16x128_f8f6f4( \
              av, bv[u], acc[t][u], 0, 0, 0, SCALE_ONE, 0, SCALE_ONE);  \
      }                                                               \
      __builtin_amdgcn_s_setprio(0);                                  \
    }                                                                 \
  } while (0)

  f32x4 acc[4][4] = {};

#pragma unroll 1
  for (int it = 0; it < 8; ++it) {
    STAGE(it);
    __syncthreads();                 // vmcnt(0) drain + barrier: tile visible
    COMPUTE();
    __syncthreads();                 // all reads done before next overwrite
  }

#undef STAGE
#undef COMPUTE

  // epilogue: descale + bf16 store of this K-half's partial (r7/r12 form)
  unsigned short* dst = pp + (size_t)ks * P_ELEMS;
#pragma unroll
  for (int t = 0; t < 4; ++t)
#pragma unroll
    for (int u = 0; u < 4; ++u)
#pragma unroll
      for (int i = 0; i < 4; ++i) {
        int n_g = n0 + wm * 64 + t * 16 + q * 4 + i;
        int c_g = c0 + wn * 64 + u * 16 + i16;
        dst[(size_t)n_g * 1024 + c_g] = f2bf(acc[t][u][i] * ADJ_DESCALE);
      }
}

// ---------------------------------------------------------------------------
extern "C" void kernel_launch(void* const* d_in, const int* in_sizes, int n_in,
                              void* d_out, int out_size, void* d_ws, size_t ws_size,
                              hipStream_t stream) {
  const float* x   = (const float*)d_in[0];
  const float* adj = (const float*)d_in[1];
  // d_in[2] = Identity (handled as the +h_nc term)
  const float* W0  = (const float*)d_in[3];
  const float* W1  = (const float*)d_in[4];
  const float* W2  = (const float*)d_in[5];
  float* out = (float*)d_out;

  char* ws = (char*)d_ws;
  unsigned char*  adj8 = (unsigned char*)ws;                   // 16 MiB
  unsigned char*  hb8  = (unsigned char*)(ws + 16777216);      //  4 MiB
  unsigned short* hnc  = (unsigned short*)(ws + 20971520);     //  8 MiB
  unsigned short* pp   = (unsigned short*)(ws + 29360128);     // p0|p1 16 MiB

  // layer 0 linear + adj quantize fused (independent, both memory-bound)
  prep<<<5120, 256, 0, stream>>>(adj, adj8, x, W0, hb8, hnc);
  gemm_f8<<<512, 256, 0, stream>>>(adj8, hb8, pp);
  // layer 1
  linear_fuse<<<dim3(64, 16), 256, 0, stream>>>(pp, hnc, W1, hb8, hnc);
  gemm_f8<<<512, 256, 0, stream>>>(adj8, hb8, pp);
  // layer 2
  linear_fuse<<<dim3(64, 16), 256, 0, stream>>>(pp, hnc, W2, hb8, hnc);
  gemm_f8<<<512, 256, 0, stream>>>(adj8, hb8, pp);
  add_out<<<2048, 256, 0, stream>>>(pp, hnc, out);
}